// Round 1
// baseline (387.485 us; speedup 1.0000x reference)
//
#include <hip/hip_runtime.h>
#include <math.h>

#define BATCH 512
#define SEQ   256
#define DIM   256
#define NHEAD 8
#define DFF   1024

// ---------- helpers ----------

__device__ __forceinline__ float block_sum256(float v, float* red) {
  // full-wave (64) reduce, then cross-wave via LDS; returns sum to ALL threads
  #pragma unroll
  for (int off = 32; off > 0; off >>= 1) v += __shfl_down(v, off, 64);
  __syncthreads();                       // protect red[] from previous use
  if ((threadIdx.x & 63) == 0) red[threadIdx.x >> 6] = v;
  __syncthreads();
  return red[0] + red[1] + red[2] + red[3];
}

__device__ __forceinline__ float dotn4(const float* __restrict__ w,
                                       const float* s, int n4) {
  const float4* w4 = (const float4*)w;
  const float4* s4 = (const float4*)s;
  float ax = 0.f, ay = 0.f, az = 0.f, aw = 0.f;
  for (int j = 0; j < n4; ++j) {
    float4 wv = w4[j]; float4 sv = s4[j];
    ax = fmaf(wv.x, sv.x, ax); ay = fmaf(wv.y, sv.y, ay);
    az = fmaf(wv.z, sv.z, az); aw = fmaf(wv.w, sv.w, aw);
  }
  return (ax + ay) + (az + aw);
}

__device__ __forceinline__ float dot256(const float* __restrict__ w, const float* s) {
  return dotn4(w, s, 64);
}

// ---------- fused kernel: one block per batch element ----------

__global__ __launch_bounds__(256) void nmstpp_fused(
    const int*   __restrict__ X,         // (B,S,9)
    const float* __restrict__ emb_act,   // (9,64)
    const float* __restrict__ emb_zone,  // (20,64)
    const float* __restrict__ lin0_w,    // (128,7)
    const float* __restrict__ lin0_b,    // (128)
    const float* __restrict__ qkv_w,     // (768,256)
    const float* __restrict__ qkv_b,     // (768)
    const float* __restrict__ attn_o_w,  // (256,256)
    const float* __restrict__ attn_o_b,  // (256)
    const float* __restrict__ ln1_g, const float* __restrict__ ln1_b,
    const float* __restrict__ ff1_w,     // (1024,256)
    const float* __restrict__ ff1_b,
    const float* __restrict__ ff2_w,     // (256,1024)
    const float* __restrict__ ff2_b,
    const float* __restrict__ ln2_g, const float* __restrict__ ln2_b,
    const float* __restrict__ relu_w,    // (256,256)
    const float* __restrict__ relu_b,
    const float* __restrict__ dT_w,      // (256,256)
    const float* __restrict__ dT_b,
    const float* __restrict__ lindT_w,   // (1,256)
    const float* __restrict__ lindT_b,   // (1)
    const float* __restrict__ zn_w,      // (257,257)
    const float* __restrict__ zn_b,
    const float* __restrict__ linzn_w,   // (20,257)
    const float* __restrict__ linzn_b,
    const float* __restrict__ act0_w,    // (277,277)
    const float* __restrict__ act0_b,
    const float* __restrict__ act1_w,    // (277,277)
    const float* __restrict__ act1_b,
    const float* __restrict__ linact_w,  // (5,277)
    const float* __restrict__ linact_b,
    float* __restrict__ out)             // (B,26)
{
  const int b = blockIdx.x;
  const int t = threadIdx.x;

  __shared__ float pe_s[SEQ];
  __shared__ float srcl[DIM];        // src at s = S-1 (fp32)
  __shared__ float qv[DIM];          // q at last position
  __shared__ float cb[NHEAD];        // bias part of scores
  __shared__ float regA[2048];       // w~ transposed [c][h]  -> later u [h][d]
  __shared__ float sc_s[2048];       // scores [h][s] -> later ffb / z1 / a0 / a1
  __shared__ float att_s[2048];      // attention transposed [s][h]
  __shared__ float ao_s[DIM];
  __shared__ float h1_s[DIM];
  __shared__ float h2_s[DIM];
  __shared__ float xr_s[DIM];
  __shared__ float fa_s[280];        // fa = [zn(20), dT, x_relu(256)] = 277
  __shared__ float znv[20];
  __shared__ float red[4];
  __shared__ float embA[9 * 65];     // +1-padded stride: bank-conflict-free gather
  __shared__ float embZ[20 * 65];
  __shared__ float l0w[128 * 7];
  __shared__ float l0b[128];

  // ---- phase 0: stage small tables, PE row ----
  for (int i = t; i < 9 * 64;  i += 256) embA[(i >> 6) * 65 + (i & 63)] = emb_act[i];
  for (int i = t; i < 20 * 64; i += 256) embZ[(i >> 6) * 65 + (i & 63)] = emb_zone[i];
  for (int i = t; i < 128 * 7; i += 256) l0w[i] = lin0_w[i];
  if (t < 128) l0b[t] = lin0_b[t];
  {
    // pe[b][s] = (s even) ? sin(b / 100^(2s/S)) : cos(...)
    float ex  = (float)(2 * t) / (float)SEQ;
    float ang = (float)b / powf(100.0f, ex);
    pe_s[t] = ((t & 1) == 0) ? sinf(ang) : cosf(ang);
  }
  __syncthreads();

  // ---- phase 1: src at the last position (channel t) ----
  {
    const int* xrow = X + (b * SEQ + (SEQ - 1)) * 9;
    int av = xrow[0], zv = xrow[1];
    float v;
    if (t < 64)        v = embA[av * 65 + t];
    else if (t < 128)  v = embZ[zv * 65 + (t - 64)];
    else {
      const float* lr = l0w + (t - 128) * 7;
      float acc = l0b[t - 128];
      #pragma unroll
      for (int j = 0; j < 7; ++j) acc = fmaf(lr[j], (float)xrow[2 + j], acc);
      v = acc;
    }
    srcl[t] = v + pe_s[SEQ - 1];
  }
  __syncthreads();

  // ---- phase 2: q = Wq @ src_last + bq ----
  qv[t] = qkv_b[t] + dot256(qkv_w + t * DIM, srcl);
  __syncthreads();

  // ---- phase 3: w~_h[d] = sum_c q[h*32+c] * Wk[h*32+c][d]  (scaled) ----
  {
    const float inv = 0.17677669529663687f;  // 1/sqrt(32)
    float acc[NHEAD];
    #pragma unroll
    for (int h = 0; h < NHEAD; ++h) acc[h] = 0.f;
    for (int c = 0; c < 32; ++c) {
      #pragma unroll
      for (int h = 0; h < NHEAD; ++h)
        acc[h] = fmaf(qv[h * 32 + c], qkv_w[(DIM + h * 32 + c) * DIM + t], acc[h]);
    }
    #pragma unroll
    for (int h = 0; h < NHEAD; ++h) regA[t * 8 + h] = acc[h] * inv;
  }
  if (t < NHEAD) {
    float accb = 0.f;
    for (int c = 0; c < 32; ++c) accb += qv[t * 32 + c] * qkv_b[DIM + t * 32 + c];
    cb[t] = accb * 0.17677669529663687f;
  }
  __syncthreads();

  // ---- phase 4: scores sc[h][s] = w~_h . src[s] + cb[h] (thread = position) ----
  {
    const int s = t;
    const int* xrow = X + (b * SEQ + s) * 9;
    int av = xrow[0], zv = xrow[1];
    float o[7];
    #pragma unroll
    for (int j = 0; j < 7; ++j) o[j] = (float)xrow[2 + j];
    float pes = pe_s[s];
    float a0=0,a1=0,a2=0,a3=0,a4=0,a5=0,a6=0,a7=0;
    for (int c = 0; c < 64; ++c) {
      float v = embA[av * 65 + c] + pes;
      float4 w0 = *(const float4*)&regA[c * 8];
      float4 w1 = *(const float4*)&regA[c * 8 + 4];
      a0=fmaf(w0.x,v,a0); a1=fmaf(w0.y,v,a1); a2=fmaf(w0.z,v,a2); a3=fmaf(w0.w,v,a3);
      a4=fmaf(w1.x,v,a4); a5=fmaf(w1.y,v,a5); a6=fmaf(w1.z,v,a6); a7=fmaf(w1.w,v,a7);
    }
    for (int c = 0; c < 64; ++c) {
      float v = embZ[zv * 65 + c] + pes;
      float4 w0 = *(const float4*)&regA[(64 + c) * 8];
      float4 w1 = *(const float4*)&regA[(64 + c) * 8 + 4];
      a0=fmaf(w0.x,v,a0); a1=fmaf(w0.y,v,a1); a2=fmaf(w0.z,v,a2); a3=fmaf(w0.w,v,a3);
      a4=fmaf(w1.x,v,a4); a5=fmaf(w1.y,v,a5); a6=fmaf(w1.z,v,a6); a7=fmaf(w1.w,v,a7);
    }
    for (int c = 0; c < 128; ++c) {
      const float* lr = l0w + c * 7;
      float v = l0b[c];
      #pragma unroll
      for (int j = 0; j < 7; ++j) v = fmaf(lr[j], o[j], v);
      v += pes;
      float4 w0 = *(const float4*)&regA[(128 + c) * 8];
      float4 w1 = *(const float4*)&regA[(128 + c) * 8 + 4];
      a0=fmaf(w0.x,v,a0); a1=fmaf(w0.y,v,a1); a2=fmaf(w0.z,v,a2); a3=fmaf(w0.w,v,a3);
      a4=fmaf(w1.x,v,a4); a5=fmaf(w1.y,v,a5); a6=fmaf(w1.z,v,a6); a7=fmaf(w1.w,v,a7);
    }
    sc_s[0*SEQ+s]=a0+cb[0]; sc_s[1*SEQ+s]=a1+cb[1];
    sc_s[2*SEQ+s]=a2+cb[2]; sc_s[3*SEQ+s]=a3+cb[3];
    sc_s[4*SEQ+s]=a4+cb[4]; sc_s[5*SEQ+s]=a5+cb[5];
    sc_s[6*SEQ+s]=a6+cb[6]; sc_s[7*SEQ+s]=a7+cb[7];
  }
  __syncthreads();

  // ---- phase 5: softmax per head (32-thread groups, 8 positions each) ----
  {
    const int h = t >> 5, idx = t & 31;
    float vals[8];
    float m = -1e30f;
    #pragma unroll
    for (int i = 0; i < 8; ++i) {
      vals[i] = sc_s[h * SEQ + idx * 8 + i];
      m = fmaxf(m, vals[i]);
    }
    #pragma unroll
    for (int off = 16; off > 0; off >>= 1) m = fmaxf(m, __shfl_xor(m, off, 32));
    float lsum = 0.f;
    #pragma unroll
    for (int i = 0; i < 8; ++i) { vals[i] = expf(vals[i] - m); lsum += vals[i]; }
    #pragma unroll
    for (int off = 16; off > 0; off >>= 1) lsum += __shfl_xor(lsum, off, 32);
    float rinv = 1.0f / lsum;
    #pragma unroll
    for (int i = 0; i < 8; ++i) att_s[(idx * 8 + i) * 8 + h] = vals[i] * rinv;
  }
  __syncthreads();

  // ---- phase 6: u_h[d] = sum_s att[h][s] * src[s][d] (thread = channel d) ----
  {
    float lw[7]; float lbv = 0.f;
    if (t >= 128) {
      const float* lr = l0w + (t - 128) * 7;
      #pragma unroll
      for (int j = 0; j < 7; ++j) lw[j] = lr[j];
      lbv = l0b[t - 128];
    }
    float acc[NHEAD];
    #pragma unroll
    for (int h = 0; h < NHEAD; ++h) acc[h] = 0.f;
    const int* Xb = X + b * SEQ * 9;
    for (int s = 0; s < SEQ; ++s) {
      const int* xrow = Xb + s * 9;
      float v;
      if (t < 64)       v = embA[xrow[0] * 65 + t];
      else if (t < 128) v = embZ[xrow[1] * 65 + (t - 64)];
      else {
        float a = lbv;
        #pragma unroll
        for (int j = 0; j < 7; ++j) a = fmaf(lw[j], (float)xrow[2 + j], a);
        v = a;
      }
      v += pe_s[s];
      float4 at0 = *(const float4*)&att_s[s * 8];
      float4 at1 = *(const float4*)&att_s[s * 8 + 4];
      acc[0]=fmaf(at0.x,v,acc[0]); acc[1]=fmaf(at0.y,v,acc[1]);
      acc[2]=fmaf(at0.z,v,acc[2]); acc[3]=fmaf(at0.w,v,acc[3]);
      acc[4]=fmaf(at1.x,v,acc[4]); acc[5]=fmaf(at1.y,v,acc[5]);
      acc[6]=fmaf(at1.z,v,acc[6]); acc[7]=fmaf(at1.w,v,acc[7]);
    }
    #pragma unroll
    for (int h = 0; h < NHEAD; ++h) regA[h * DIM + t] = acc[h];  // u overlays w~
  }
  __syncthreads();

  // ---- phase 7: ao[c] = Wv[c] . u_{h(c)} + bv[c] ----
  {
    const int h = t >> 5;
    ao_s[t] = qkv_b[2 * DIM + t] + dot256(qkv_w + (2 * DIM + t) * DIM, regA + h * DIM);
  }
  __syncthreads();

  // ---- phase 8: h1 = LN1(src_last + attn_o(ao)) ----
  {
    float tv = srcl[t] + attn_o_b[t] + dot256(attn_o_w + t * DIM, ao_s);
    float mean = block_sum256(tv, red) * (1.0f / 256.0f);
    float dv = tv - mean;
    float var = block_sum256(dv * dv, red) * (1.0f / 256.0f);
    h1_s[t] = dv / sqrtf(var + 1e-5f) * ln1_g[t] + ln1_b[t];
  }
  __syncthreads();

  // ---- phase 9: f = relu(ff1 @ h1 + b) in sc_s[0..1023] ----
  #pragma unroll
  for (int r = 0; r < 4; ++r) {
    int j = r * 256 + t;
    float v = ff1_b[j] + dot256(ff1_w + j * DIM, h1_s);
    sc_s[j] = fmaxf(v, 0.f);
  }
  __syncthreads();

  // ---- phase 10: h2 = LN2(h1 + ff2 @ f + b) ----
  {
    float g = ff2_b[t] + dotn4(ff2_w + t * DFF, sc_s, 256);
    float tv = h1_s[t] + g;
    float mean = block_sum256(tv, red) * (1.0f / 256.0f);
    float dv = tv - mean;
    float var = block_sum256(dv * dv, red) * (1.0f / 256.0f);
    h2_s[t] = dv / sqrtf(var + 1e-5f) * ln2_g[t] + ln2_b[t];
  }
  __syncthreads();

  // ---- phase 11: x_relu = relu_w @ h2 + b (no activation in reference) ----
  xr_s[t] = relu_b[t] + dot256(relu_w + t * DIM, h2_s);
  __syncthreads();

  // ---- phase 12: dT = lindT @ (dT_w @ x_relu + b) + b ----
  float dTv;
  {
    float d1 = dT_b[t] + dot256(dT_w + t * DIM, xr_s);
    dTv = block_sum256(lindT_w[t] * d1, red) + lindT_b[0];
  }

  // ---- phase 13: zn path; znin = [dT, x_relu] (257) ----
  float* z1 = sc_s + 1024;   // 257 floats
  {
    const float* wr = zn_w + t * 257;
    float acc = zn_b[t] + wr[0] * dTv;
    for (int j = 0; j < 256; ++j) acc = fmaf(wr[1 + j], xr_s[j], acc);
    z1[t] = acc;
    if (t == 0) {
      const float* wr2 = zn_w + 256 * 257;
      float a2 = zn_b[256] + wr2[0] * dTv;
      for (int j = 0; j < 256; ++j) a2 = fmaf(wr2[1 + j], xr_s[j], a2);
      z1[256] = a2;
    }
  }
  __syncthreads();
  // zn = linzn @ z1 + b; build fa = [zn(20), dT, x_relu(256)]
  fa_s[21 + t] = xr_s[t];
  if (t == 20) fa_s[20] = dTv;
  if (t < 20) {
    const float* wr = linzn_w + t * 257;
    float acc = linzn_b[t];
    for (int j = 0; j < 257; ++j) acc = fmaf(wr[j], z1[j], acc);
    znv[t] = acc;
    fa_s[t] = acc;
  }
  __syncthreads();

  // ---- phase 14: ac = linact @ act1 @ act0 @ fa ----
  float* a0v = sc_s + 1312;  // 277 floats
  for (int i = t; i < 277; i += 256) {
    const float* wr = act0_w + i * 277;
    float acc = act0_b[i];
    for (int j = 0; j < 277; ++j) acc = fmaf(wr[j], fa_s[j], acc);
    a0v[i] = acc;
  }
  __syncthreads();
  float* a1v = sc_s + 1024;  // reuse z1 region (z1 dead)
  for (int i = t; i < 277; i += 256) {
    const float* wr = act1_w + i * 277;
    float acc = act1_b[i];
    for (int j = 0; j < 277; ++j) acc = fmaf(wr[j], a0v[j], acc);
    a1v[i] = acc;
  }
  __syncthreads();

  // ---- phase 15: outputs: out[b] = [dT, zn(20), ac(5)] ----
  if (t < 5) {
    const float* wr = linact_w + t * 277;
    float acc = linact_b[t];
    for (int j = 0; j < 277; ++j) acc = fmaf(wr[j], a1v[j], acc);
    out[b * 26 + 21 + t] = acc;
  }
  if (t == 0)  out[b * 26] = dTv;
  if (t < 20)  out[b * 26 + 1 + t] = znv[t];
}

// ---------- launcher ----------

extern "C" void kernel_launch(void* const* d_in, const int* in_sizes, int n_in,
                              void* d_out, int out_size, void* d_ws, size_t ws_size,
                              hipStream_t stream) {
  (void)in_sizes; (void)n_in; (void)d_ws; (void)ws_size; (void)out_size;
  const int*   X        = (const int*)  d_in[0];
  const float* emb_act  = (const float*)d_in[1];
  const float* emb_zone = (const float*)d_in[2];
  const float* lin0_w   = (const float*)d_in[3];
  const float* lin0_b   = (const float*)d_in[4];
  const float* qkv_w    = (const float*)d_in[5];
  const float* qkv_b    = (const float*)d_in[6];
  const float* attn_o_w = (const float*)d_in[7];
  const float* attn_o_b = (const float*)d_in[8];
  const float* ln1_g    = (const float*)d_in[9];
  const float* ln1_b    = (const float*)d_in[10];
  const float* ff1_w    = (const float*)d_in[11];
  const float* ff1_b    = (const float*)d_in[12];
  const float* ff2_w    = (const float*)d_in[13];
  const float* ff2_b    = (const float*)d_in[14];
  const float* ln2_g    = (const float*)d_in[15];
  const float* ln2_b    = (const float*)d_in[16];
  const float* relu_w   = (const float*)d_in[17];
  const float* relu_b   = (const float*)d_in[18];
  const float* dT_w     = (const float*)d_in[19];
  const float* dT_b     = (const float*)d_in[20];
  const float* lindT_w  = (const float*)d_in[21];
  const float* lindT_b  = (const float*)d_in[22];
  const float* zn_w     = (const float*)d_in[23];
  const float* zn_b     = (const float*)d_in[24];
  const float* linzn_w  = (const float*)d_in[25];
  const float* linzn_b  = (const float*)d_in[26];
  const float* act0_w   = (const float*)d_in[27];
  const float* act0_b   = (const float*)d_in[28];
  const float* act1_w   = (const float*)d_in[29];
  const float* act1_b   = (const float*)d_in[30];
  const float* linact_w = (const float*)d_in[31];
  const float* linact_b = (const float*)d_in[32];
  float* out = (float*)d_out;

  nmstpp_fused<<<dim3(BATCH), dim3(256), 0, stream>>>(
      X, emb_act, emb_zone, lin0_w, lin0_b, qkv_w, qkv_b, attn_o_w, attn_o_b,
      ln1_g, ln1_b, ff1_w, ff1_b, ff2_w, ff2_b, ln2_g, ln2_b,
      relu_w, relu_b, dT_w, dT_b, lindT_w, lindT_b, zn_w, zn_b,
      linzn_w, linzn_b, act0_w, act0_b, act1_w, act1_b, linact_w, linact_b,
      out);
}

// Round 2
// 363.366 us; speedup vs baseline: 1.0664x; 1.0664x over previous
//
#include <hip/hip_runtime.h>
#include <math.h>

#define BATCH 512
#define SEQ   256
#define DIM   256
#define NHEAD 8
#define DFF   1024

// ---------- helpers ----------

__device__ __forceinline__ float block_sum256(float v, float* red) {
  #pragma unroll
  for (int off = 32; off > 0; off >>= 1) v += __shfl_down(v, off, 64);
  __syncthreads();
  if ((threadIdx.x & 63) == 0) red[threadIdx.x >> 6] = v;
  __syncthreads();
  return red[0] + red[1] + red[2] + red[3];
}

__device__ __forceinline__ float dotn4(const float* __restrict__ w,
                                       const float* s, int n4) {
  const float4* w4 = (const float4*)w;
  const float4* s4 = (const float4*)s;
  float ax = 0.f, ay = 0.f, az = 0.f, aw = 0.f;
  for (int j = 0; j < n4; ++j) {
    float4 wv = w4[j]; float4 sv = s4[j];
    ax = fmaf(wv.x, sv.x, ax); ay = fmaf(wv.y, sv.y, ay);
    az = fmaf(wv.z, sv.z, az); aw = fmaf(wv.w, sv.w, aw);
  }
  return (ax + ay) + (az + aw);
}

__device__ __forceinline__ float dot256(const float* __restrict__ w, const float* s) {
  return dotn4(w, s, 64);
}

// ---------- fused kernel: one block per batch element ----------

__global__ __launch_bounds__(256) void nmstpp_fused(
    const int*   __restrict__ X,         // (B,S,9)
    const float* __restrict__ emb_act,   // (9,64)
    const float* __restrict__ emb_zone,  // (20,64)
    const float* __restrict__ lin0_w,    // (128,7)
    const float* __restrict__ lin0_b,    // (128)
    const float* __restrict__ qkv_w,     // (768,256)
    const float* __restrict__ qkv_b,     // (768)
    const float* __restrict__ attn_o_w,  // (256,256)
    const float* __restrict__ attn_o_b,  // (256)
    const float* __restrict__ ln1_g, const float* __restrict__ ln1_b,
    const float* __restrict__ ff1_w,     // (1024,256)
    const float* __restrict__ ff1_b,
    const float* __restrict__ ff2_w,     // (256,1024)
    const float* __restrict__ ff2_b,
    const float* __restrict__ ln2_g, const float* __restrict__ ln2_b,
    const float* __restrict__ relu_w,    // (256,256)
    const float* __restrict__ relu_b,
    const float* __restrict__ dT_w,      // (256,256)
    const float* __restrict__ dT_b,
    const float* __restrict__ lindT_w,   // (1,256)
    const float* __restrict__ lindT_b,   // (1)
    const float* __restrict__ zn_w,      // (257,257)
    const float* __restrict__ zn_b,
    const float* __restrict__ linzn_w,   // (20,257)
    const float* __restrict__ linzn_b,
    const float* __restrict__ act0_w,    // (277,277)
    const float* __restrict__ act0_b,
    const float* __restrict__ act1_w,    // (277,277)
    const float* __restrict__ act1_b,
    const float* __restrict__ linact_w,  // (5,277)
    const float* __restrict__ linact_b,
    float* __restrict__ out)             // (B,26)
{
  const int b = blockIdx.x;
  const int t = threadIdx.x;

  __shared__ float pe_s[SEQ];
  __shared__ float srcl[DIM];
  __shared__ float qv[DIM];
  __shared__ float cb[NHEAD];
  __shared__ float regA[2048];       // w~ [c][h] -> later u [h][d]
  __shared__ float sc_s[2048];       // scores [h][s] -> ffb / z1 / a0 / a1
  __shared__ float att_s[2048];      // attention [s][h]
  __shared__ float ao_s[DIM];
  __shared__ float h1_s[DIM];
  __shared__ float h2_s[DIM];
  __shared__ float xr_s[DIM];
  __shared__ float fa_s[280];
  __shared__ float znv[20];
  __shared__ float red[4];
  __shared__ float embA[9 * 65];     // +1-padded stride
  __shared__ float embZ[20 * 65];
  __shared__ float l0w[128 * 7];
  __shared__ float l0b[128];
  // staged X for this batch
  __shared__ int   Xa[SEQ];
  __shared__ int   Xz[SEQ];
  __shared__ float Xo[SEQ * 7];
  // score decomposition tables
  __shared__ float scA[9 * 8];       // [a][h]
  __shared__ float scZ[20 * 8];      // [z][h]
  __shared__ float mHJ[8 * 8];       // [h][j], j<7
  __shared__ float biasO8[8];
  __shared__ float wsum8[8];
  // attention histogram tables
  __shared__ float attA[8 * 9];      // [h][a]
  __shared__ float attZ[8 * 20];     // [h][z]
  __shared__ float oAcc[8 * 7];      // [h][j]
  __shared__ float peAcc8[8];

  // ---- phase 0: stage tables, X rows, PE row ----
  for (int i = t; i < 9 * 64;  i += 256) embA[(i >> 6) * 65 + (i & 63)] = emb_act[i];
  for (int i = t; i < 20 * 64; i += 256) embZ[(i >> 6) * 65 + (i & 63)] = emb_zone[i];
  for (int i = t; i < 128 * 7; i += 256) l0w[i] = lin0_w[i];
  if (t < 128) l0b[t] = lin0_b[t];
  {
    const int* xrow = X + (b * SEQ + t) * 9;
    Xa[t] = xrow[0];
    Xz[t] = xrow[1];
    #pragma unroll
    for (int j = 0; j < 7; ++j) Xo[t * 7 + j] = (float)xrow[2 + j];
  }
  {
    // pe[b][s] = (s even) ? sin(b / 100^(2s/S)) : cos(...)
    float ex  = (float)(2 * t) / (float)SEQ;
    float ang = (float)b * exp2f(-ex * 6.643856189774724f);  // 100^-ex
    pe_s[t] = ((t & 1) == 0) ? sinf(ang) : cosf(ang);
  }
  __syncthreads();

  // ---- phase 1: src at the last position (channel t) ----
  {
    int av = Xa[SEQ - 1], zv = Xz[SEQ - 1];
    float v;
    if (t < 64)        v = embA[av * 65 + t];
    else if (t < 128)  v = embZ[zv * 65 + (t - 64)];
    else {
      const float* lr = l0w + (t - 128) * 7;
      float acc = l0b[t - 128];
      #pragma unroll
      for (int j = 0; j < 7; ++j) acc = fmaf(lr[j], Xo[(SEQ - 1) * 7 + j], acc);
      v = acc;
    }
    srcl[t] = v + pe_s[SEQ - 1];
  }
  __syncthreads();

  // ---- phase 2: q = Wq @ src_last + bq ----
  qv[t] = qkv_b[t] + dot256(qkv_w + t * DIM, srcl);
  __syncthreads();

  // ---- phase 3: w~_h[d] = (1/sqrt(hd)) sum_c q[h*32+c] * Wk[h*32+c][d] ----
  {
    const float inv = 0.17677669529663687f;  // 1/sqrt(32)
    float acc[NHEAD];
    #pragma unroll
    for (int h = 0; h < NHEAD; ++h) acc[h] = 0.f;
    for (int c = 0; c < 32; ++c) {
      #pragma unroll
      for (int h = 0; h < NHEAD; ++h)
        acc[h] = fmaf(qv[h * 32 + c], qkv_w[(DIM + h * 32 + c) * DIM + t], acc[h]);
    }
    #pragma unroll
    for (int h = 0; h < NHEAD; ++h) regA[t * 8 + h] = acc[h] * inv;
  }
  __syncthreads();

  // ---- phase 3.5: collapse scores into lookup tables ----
  // sc[h][s] = scA[a_s][h] + scZ[z_s][h] + m[h].o_s + biasO[h] + pe[s]*wsum[h] + cb[h]
  {
    #pragma unroll
    for (int pass = 0; pass < 2; ++pass) {
      int slot = (pass == 0) ? t : 256 + t;
      if (slot < 296) {
        int h = slot / 37, k = slot - h * 37;
        if (k < 9) {
          float acc = 0.f;
          for (int c = 0; c < 64; ++c) acc = fmaf(regA[c * 8 + h], embA[k * 65 + c], acc);
          scA[k * 8 + h] = acc;
        } else if (k < 29) {
          int z = k - 9; float acc = 0.f;
          for (int c = 0; c < 64; ++c) acc = fmaf(regA[(64 + c) * 8 + h], embZ[z * 65 + c], acc);
          scZ[z * 8 + h] = acc;
        } else if (k < 36) {
          int j = k - 29; float acc = 0.f;
          for (int kk = 0; kk < 128; ++kk) acc = fmaf(regA[(128 + kk) * 8 + h], l0w[kk * 7 + j], acc);
          mHJ[h * 8 + j] = acc;
        } else {
          float acc = 0.f;
          for (int c = 0; c < 256; ++c) acc += regA[c * 8 + h];
          wsum8[h] = acc;
        }
      }
      if (pass == 1) {
        if (t >= 40 && t < 48) {
          int h = t - 40; float acc = 0.f;
          for (int kk = 0; kk < 128; ++kk) acc = fmaf(regA[(128 + kk) * 8 + h], l0b[kk], acc);
          biasO8[h] = acc;
        } else if (t >= 48 && t < 56) {
          int h = t - 48; float acc = 0.f;
          for (int c = 0; c < 32; ++c) acc += qv[h * 32 + c] * qkv_b[DIM + h * 32 + c];
          cb[h] = acc * 0.17677669529663687f;
        }
      }
    }
  }
  __syncthreads();

  // ---- phase 4: scores via tables (thread = position) ----
  {
    const int s = t;
    int av = Xa[s], zv = Xz[s];
    float o[7];
    #pragma unroll
    for (int j = 0; j < 7; ++j) o[j] = Xo[s * 7 + j];
    float pes = pe_s[s];
    #pragma unroll
    for (int h = 0; h < NHEAD; ++h) {
      float acc = scA[av * 8 + h] + scZ[zv * 8 + h] + biasO8[h] + cb[h];
      acc = fmaf(pes, wsum8[h], acc);
      #pragma unroll
      for (int j = 0; j < 7; ++j) acc = fmaf(mHJ[h * 8 + j], o[j], acc);
      sc_s[h * SEQ + s] = acc;
    }
  }
  __syncthreads();

  // ---- phase 5: softmax per head (32-thread groups, 8 positions each) ----
  {
    const int h = t >> 5, idx = t & 31;
    float vals[8];
    float m = -1e30f;
    #pragma unroll
    for (int i = 0; i < 8; ++i) {
      vals[i] = sc_s[h * SEQ + idx * 8 + i];
      m = fmaxf(m, vals[i]);
    }
    #pragma unroll
    for (int off = 16; off > 0; off >>= 1) m = fmaxf(m, __shfl_xor(m, off, 32));
    float lsum = 0.f;
    #pragma unroll
    for (int i = 0; i < 8; ++i) { vals[i] = expf(vals[i] - m); lsum += vals[i]; }
    #pragma unroll
    for (int off = 16; off > 0; off >>= 1) lsum += __shfl_xor(lsum, off, 32);
    float rinv = 1.0f / lsum;
    #pragma unroll
    for (int i = 0; i < 8; ++i) att_s[(idx * 8 + i) * 8 + h] = vals[i] * rinv;
  }
  __syncthreads();

  // ---- phase 6a: attention-weighted histograms / moments ----
  {
    #pragma unroll
    for (int pass = 0; pass < 2; ++pass) {
      int slot = (pass == 0) ? t : 256 + t;
      if (slot < 296) {
        int h = slot / 37, k = slot - h * 37;
        float acc = 0.f;
        if (k < 29) {
          int mybin = (k < 9) ? k : (k - 9);
          const int* bins = (k < 9) ? Xa : Xz;
          for (int s = 0; s < SEQ; ++s) {
            float at = att_s[s * 8 + h];
            acc += (bins[s] == mybin) ? at : 0.f;
          }
          if (k < 9) attA[h * 9 + k] = acc; else attZ[h * 20 + (k - 9)] = acc;
        } else if (k < 36) {
          int j = k - 29;
          for (int s = 0; s < SEQ; ++s) acc = fmaf(att_s[s * 8 + h], Xo[s * 7 + j], acc);
          oAcc[h * 7 + j] = acc;
        } else {
          for (int s = 0; s < SEQ; ++s) acc = fmaf(att_s[s * 8 + h], pe_s[s], acc);
          peAcc8[h] = acc;
        }
      }
    }
  }
  __syncthreads();

  // ---- phase 6b: reconstruct u_h[d] (thread = channel d) ----
  {
    float acc[NHEAD];
    #pragma unroll
    for (int h = 0; h < NHEAD; ++h) acc[h] = peAcc8[h];
    if (t < 64) {
      for (int a = 0; a < 9; ++a) {
        float ev = embA[a * 65 + t];
        #pragma unroll
        for (int h = 0; h < NHEAD; ++h) acc[h] = fmaf(attA[h * 9 + a], ev, acc[h]);
      }
    } else if (t < 128) {
      int d = t - 64;
      for (int z = 0; z < 20; ++z) {
        float ev = embZ[z * 65 + d];
        #pragma unroll
        for (int h = 0; h < NHEAD; ++h) acc[h] = fmaf(attZ[h * 20 + z], ev, acc[h]);
      }
    } else {
      int kk = t - 128;
      #pragma unroll
      for (int j = 0; j < 7; ++j) {
        float ov = l0w[kk * 7 + j];
        #pragma unroll
        for (int h = 0; h < NHEAD; ++h) acc[h] = fmaf(oAcc[h * 7 + j], ov, acc[h]);
      }
      #pragma unroll
      for (int h = 0; h < NHEAD; ++h) acc[h] += l0b[kk];   // sum(att)=1
    }
    #pragma unroll
    for (int h = 0; h < NHEAD; ++h) regA[h * DIM + t] = acc[h];
  }
  __syncthreads();

  // ---- phase 7: ao[c] = Wv[c] . u_{h(c)} + bv[c] ----
  {
    const int h = t >> 5;
    ao_s[t] = qkv_b[2 * DIM + t] + dot256(qkv_w + (2 * DIM + t) * DIM, regA + h * DIM);
  }
  __syncthreads();

  // ---- phase 8: h1 = LN1(src_last + attn_o(ao)) ----
  {
    float tv = srcl[t] + attn_o_b[t] + dot256(attn_o_w + t * DIM, ao_s);
    float mean = block_sum256(tv, red) * (1.0f / 256.0f);
    float dv = tv - mean;
    float var = block_sum256(dv * dv, red) * (1.0f / 256.0f);
    h1_s[t] = dv / sqrtf(var + 1e-5f) * ln1_g[t] + ln1_b[t];
  }
  __syncthreads();

  // ---- phase 9: f = relu(ff1 @ h1 + b) ----
  #pragma unroll
  for (int r = 0; r < 4; ++r) {
    int j = r * 256 + t;
    float v = ff1_b[j] + dot256(ff1_w + j * DIM, h1_s);
    sc_s[j] = fmaxf(v, 0.f);
  }
  __syncthreads();

  // ---- phase 10: h2 = LN2(h1 + ff2 @ f + b) ----
  {
    float g = ff2_b[t] + dotn4(ff2_w + t * DFF, sc_s, 256);
    float tv = h1_s[t] + g;
    float mean = block_sum256(tv, red) * (1.0f / 256.0f);
    float dv = tv - mean;
    float var = block_sum256(dv * dv, red) * (1.0f / 256.0f);
    h2_s[t] = dv / sqrtf(var + 1e-5f) * ln2_g[t] + ln2_b[t];
  }
  __syncthreads();

  // ---- phase 11: x_relu = relu_w @ h2 + b ----
  xr_s[t] = relu_b[t] + dot256(relu_w + t * DIM, h2_s);
  __syncthreads();

  // ---- phase 12: dT ----
  float dTv;
  {
    float d1 = dT_b[t] + dot256(dT_w + t * DIM, xr_s);
    dTv = block_sum256(lindT_w[t] * d1, red) + lindT_b[0];
  }

  // ---- phase 13: zn path ----
  float* z1 = sc_s + 1024;   // 257 floats
  {
    const float* wr = zn_w + t * 257;
    float acc = zn_b[t] + wr[0] * dTv;
    for (int j = 0; j < 256; ++j) acc = fmaf(wr[1 + j], xr_s[j], acc);
    z1[t] = acc;
    if (t == 0) {
      const float* wr2 = zn_w + 256 * 257;
      float a2 = zn_b[256] + wr2[0] * dTv;
      for (int j = 0; j < 256; ++j) a2 = fmaf(wr2[1 + j], xr_s[j], a2);
      z1[256] = a2;
    }
  }
  __syncthreads();
  fa_s[21 + t] = xr_s[t];
  if (t == 20) fa_s[20] = dTv;
  if (t < 20) {
    const float* wr = linzn_w + t * 257;
    float acc = linzn_b[t];
    for (int j = 0; j < 257; ++j) acc = fmaf(wr[j], z1[j], acc);
    znv[t] = acc;
    fa_s[t] = acc;
  }
  __syncthreads();

  // ---- phase 14: ac = linact @ act1 @ act0 @ fa ----
  float* a0v = sc_s + 1312;
  for (int i = t; i < 277; i += 256) {
    const float* wr = act0_w + i * 277;
    float acc = act0_b[i];
    for (int j = 0; j < 277; ++j) acc = fmaf(wr[j], fa_s[j], acc);
    a0v[i] = acc;
  }
  __syncthreads();
  float* a1v = sc_s + 1024;
  for (int i = t; i < 277; i += 256) {
    const float* wr = act1_w + i * 277;
    float acc = act1_b[i];
    for (int j = 0; j < 277; ++j) acc = fmaf(wr[j], a0v[j], acc);
    a1v[i] = acc;
  }
  __syncthreads();

  // ---- phase 15: outputs ----
  if (t < 5) {
    const float* wr = linact_w + t * 277;
    float acc = linact_b[t];
    for (int j = 0; j < 277; ++j) acc = fmaf(wr[j], a1v[j], acc);
    out[b * 26 + 21 + t] = acc;
  }
  if (t == 0)  out[b * 26] = dTv;
  if (t < 20)  out[b * 26 + 1 + t] = znv[t];
}

// ---------- launcher ----------

extern "C" void kernel_launch(void* const* d_in, const int* in_sizes, int n_in,
                              void* d_out, int out_size, void* d_ws, size_t ws_size,
                              hipStream_t stream) {
  (void)in_sizes; (void)n_in; (void)d_ws; (void)ws_size; (void)out_size;
  const int*   X        = (const int*)  d_in[0];
  const float* emb_act  = (const float*)d_in[1];
  const float* emb_zone = (const float*)d_in[2];
  const float* lin0_w   = (const float*)d_in[3];
  const float* lin0_b   = (const float*)d_in[4];
  const float* qkv_w    = (const float*)d_in[5];
  const float* qkv_b    = (const float*)d_in[6];
  const float* attn_o_w = (const float*)d_in[7];
  const float* attn_o_b = (const float*)d_in[8];
  const float* ln1_g    = (const float*)d_in[9];
  const float* ln1_b    = (const float*)d_in[10];
  const float* ff1_w    = (const float*)d_in[11];
  const float* ff1_b    = (const float*)d_in[12];
  const float* ff2_w    = (const float*)d_in[13];
  const float* ff2_b    = (const float*)d_in[14];
  const float* ln2_g    = (const float*)d_in[15];
  const float* ln2_b    = (const float*)d_in[16];
  const float* relu_w   = (const float*)d_in[17];
  const float* relu_b   = (const float*)d_in[18];
  const float* dT_w     = (const float*)d_in[19];
  const float* dT_b     = (const float*)d_in[20];
  const float* lindT_w  = (const float*)d_in[21];
  const float* lindT_b  = (const float*)d_in[22];
  const float* zn_w     = (const float*)d_in[23];
  const float* zn_b     = (const float*)d_in[24];
  const float* linzn_w  = (const float*)d_in[25];
  const float* linzn_b  = (const float*)d_in[26];
  const float* act0_w   = (const float*)d_in[27];
  const float* act0_b   = (const float*)d_in[28];
  const float* act1_w   = (const float*)d_in[29];
  const float* act1_b   = (const float*)d_in[30];
  const float* linact_w = (const float*)d_in[31];
  const float* linact_b = (const float*)d_in[32];
  float* out = (float*)d_out;

  nmstpp_fused<<<dim3(BATCH), dim3(256), 0, stream>>>(
      X, emb_act, emb_zone, lin0_w, lin0_b, qkv_w, qkv_b, attn_o_w, attn_o_b,
      ln1_g, ln1_b, ff1_w, ff1_b, ff2_w, ff2_b, ln2_g, ln2_b,
      relu_w, relu_b, dT_w, dT_b, lindT_w, lindT_b, zn_w, zn_b,
      linzn_w, linzn_b, act0_w, act0_b, act1_w, act1_b, linact_w, linact_b,
      out);
}